// Round 16
// baseline (132.760 us; speedup 1.0000x reference)
//
#include <hip/hip_runtime.h>
#include <math.h>

typedef __bf16 bf16x8 __attribute__((ext_vector_type(8)));
typedef __bf16 bf16x2 __attribute__((ext_vector_type(2)));
typedef float f32x4 __attribute__((ext_vector_type(4)));
typedef float f32x16 __attribute__((ext_vector_type(16)));
typedef unsigned u32x2v __attribute__((ext_vector_type(2)));
typedef unsigned short u16;

#define NQ 8192
#define DMODEL 512
#define NHEAD 8
#define DH 64
#define NC 2048
#define NIDX 100000

__device__ __forceinline__ u16 f2bf(float f) {
    unsigned u = __float_as_uint(f);
    u += 0x7fffu + ((u >> 16) & 1u);
    return (u16)(u >> 16);
}
__device__ __forceinline__ float bf2f(u16 h) {
    return __uint_as_float(((unsigned)h) << 16);
}
__device__ __forceinline__ unsigned pk2(float a, float b) {
    bf16x2 t; t[0] = (__bf16)a; t[1] = (__bf16)b;   // v_cvt_pk_bf16_f32 (RNE)
    return __builtin_bit_cast(unsigned, t);
}
__device__ __forceinline__ void plswap(unsigned& a, unsigned& b) {
    u32x2v r = __builtin_amdgcn_permlane32_swap(a, b, false, false);
    a = r[0]; b = r[1];
}
// swizzled u32 index into sO[32][256]: 16B-block XOR by row
__device__ __forceinline__ int soff(int q, int col) {
    return q * 256 + ((((col >> 2) ^ (q & 7)) << 2) | (col & 3));
}

// ---------------- bf16 GEMM core: C = A[M][K] * Bt[N][K]^T + bias[N] (+bias_b) --------
// A_MODE: 0 = bf16 row-major; 1 = f32 row-major (cvt during staging);
//         3 = f32 TRANSPOSED source (A[i][k] = src[k*M + i]) staged cooperatively
//             via coalesced row reads + LDS transpose (no per-lane gathers).
// B_MODE: 0 = bf16 row-major; 1 = f32 row-major.
// OUT_T : 0 = row-major [M][N]; 1 = V fragment-major; 2 = K fragment-major.
template <int A_MODE, int B_MODE, int OUT_T>
__device__ __forceinline__ void gemm_bt_body(
    const void* __restrict__ A_, const void* __restrict__ Bt_,
    const float* __restrict__ bias, const float* __restrict__ bias_b,
    u16* __restrict__ Cmat, int M, int N, int K, int bx, int by)
{
    constexpr int LDP = 40;
    __shared__ __align__(16) u16 As[128 * LDP];
    __shared__ __align__(16) u16 Bs[128 * LDP];
    int tid = threadIdx.x;
    int lane = tid & 63, wid = tid >> 6;
    int wrow = (wid >> 1) * 64, wcol = (wid & 1) * 64;
    int m0 = by * 128, n0 = bx * 128;
    int lr = lane & 15, lg = lane >> 4;
    f32x4 acc[4][4] = {};

    for (int k0 = 0; k0 < K; k0 += 32) {
        if (A_MODE == 3) {
            // stage A-tile [128 m][32 k] from f32 src[k][m]: coalesced row reads
#pragma unroll
            for (int i = 0; i < 4; i++) {
                int linear = i * 256 + tid;           // 0..1023
                int kk = linear >> 5;                 // 0..31
                int c4 = (linear & 31) * 4;           // 0..124
                float4 f = *(const float4*)((const float*)A_ + (size_t)(k0 + kk) * M + m0 + c4);
                As[(c4 + 0) * LDP + kk] = f2bf(f.x);
                As[(c4 + 1) * LDP + kk] = f2bf(f.y);
                As[(c4 + 2) * LDP + kk] = f2bf(f.z);
                As[(c4 + 3) * LDP + kk] = f2bf(f.w);
            }
        }
#pragma unroll
        for (int c = 0; c < 2; c++) {
            int ch = tid + c * 256;
            int row = ch >> 2, colc = (ch & 3) * 8;
            if (A_MODE != 3) {
                uint4 av;
                if (A_MODE == 1) {
                    const float* Af = (const float*)A_;
                    float4 a0 = *(const float4*)(Af + (size_t)(m0 + row) * K + k0 + colc);
                    float4 a1 = *(const float4*)(Af + (size_t)(m0 + row) * K + k0 + colc + 4);
                    av.x = pk2(a0.x, a0.y); av.y = pk2(a0.z, a0.w);
                    av.z = pk2(a1.x, a1.y); av.w = pk2(a1.z, a1.w);
                } else {
                    av = *(const uint4*)((const u16*)A_ + (size_t)(m0 + row) * K + k0 + colc);
                }
                *(uint4*)(&As[row * LDP + colc]) = av;
            }
            uint4 bv;
            if (B_MODE == 1) {
                const float* Bf = (const float*)Bt_;
                float4 b0 = *(const float4*)(Bf + (size_t)(n0 + row) * K + k0 + colc);
                float4 b1 = *(const float4*)(Bf + (size_t)(n0 + row) * K + k0 + colc + 4);
                bv.x = pk2(b0.x, b0.y); bv.y = pk2(b0.z, b0.w);
                bv.z = pk2(b1.x, b1.y); bv.w = pk2(b1.z, b1.w);
            } else {
                bv = *(const uint4*)((const u16*)Bt_ + (size_t)(n0 + row) * K + k0 + colc);
            }
            *(uint4*)(&Bs[row * LDP + colc]) = bv;
        }
        __syncthreads();
        bf16x8 af[4], bfr[4];
#pragma unroll
        for (int m = 0; m < 4; m++)
            af[m] = *(const bf16x8*)(&As[(wrow + m * 16 + lr) * LDP + lg * 8]);
#pragma unroll
        for (int n = 0; n < 4; n++)
            bfr[n] = *(const bf16x8*)(&Bs[(wcol + n * 16 + lr) * LDP + lg * 8]);
#pragma unroll
        for (int m = 0; m < 4; m++)
#pragma unroll
            for (int n = 0; n < 4; n++)
                acc[m][n] = __builtin_amdgcn_mfma_f32_16x16x32_bf16(af[m], bfr[n], acc[m][n], 0, 0, 0);
        __syncthreads();
    }
#pragma unroll
    for (int n = 0; n < 4; n++) {
        int col = n0 + wcol + n * 16 + lr;
        float bv = (bias ? bias[col] : 0.0f) + (bias_b ? bias_b[col] : 0.0f);
#pragma unroll
        for (int m = 0; m < 4; m++) {
            int rbase = m0 + wrow + m * 16 + lg * 4;
            if (OUT_T == 1) {
                int hh = col >> 6, T = (col >> 5) & 1, ql = col & 31;
                int t = rbase >> 5, cc = rbase & 31;
                int u = ((cc >> 4) * 2 + ((cc >> 3) & 1)) * 2 + T;
                size_t off = (size_t)hh * 131072 + (size_t)t * 2048 + u * 256 + ql * 8 + (cc & 7);
                ushort4 o4;
                o4.x = f2bf(acc[m][n][0] + bv);
                o4.y = f2bf(acc[m][n][1] + bv);
                o4.z = f2bf(acc[m][n][2] + bv);
                o4.w = f2bf(acc[m][n][3] + bv);
                *(ushort4*)(Cmat + off) = o4;
            } else if (OUT_T == 2) {
                int hh = col >> 6, m2 = (col >> 4) & 3, h2 = (col >> 3) & 1, jj = col & 7;
                size_t ub = (size_t)hh * 131072 + (size_t)(m2 * 2 + h2) * 256 + jj;
#pragma unroll
                for (int r = 0; r < 4; r++) {
                    int c = rbase + r;
                    Cmat[ub + (size_t)(c >> 5) * 2048 + (c & 31) * 8] = f2bf(acc[m][n][r] + bv);
                }
            } else {
#pragma unroll
                for (int r = 0; r < 4; r++)
                    Cmat[(size_t)(rbase + r) * N + col] = f2bf(acc[m][n][r] + bv);
            }
        }
    }
}

// ---------------- prep: WcombT GEMM + Wk/Wv transposes + parallel bcomb ----------------
// bid 0..15   : WcombT = Wq^T @ Wp^T   (A staged coalesced via A_MODE=3)
// bid 16..527 : Wk^T (16..271), Wv^T (272..527)
// bid 528..591: bcomb partial sums (8 k-rows each, atomicAdd; bcomb pre-zeroed)
__global__ __launch_bounds__(256) void k_prep2(
    const float* __restrict__ Wq, const float* __restrict__ Wk, const float* __restrict__ Wv,
    const float* __restrict__ Wp, const float* __restrict__ bp,
    u16* __restrict__ Wk_t, u16* __restrict__ Wv_t,
    u16* __restrict__ WcombT, float* __restrict__ bcomb)
{
    __shared__ float tile[32][33];
    int bid = blockIdx.x, tid = threadIdx.x;
    if (bid < 16) {
        gemm_bt_body<3, 1, 0>(Wq, Wp, nullptr, nullptr, WcombT, DMODEL, DMODEL, DMODEL,
                              bid & 3, bid >> 2);
    } else if (bid < 528) {
        const float* W; u16* Wt; int tb;
        if (bid < 272) { W = Wk; Wt = Wk_t; tb = bid - 16; }
        else           { W = Wv; Wt = Wv_t; tb = bid - 272; }
        int c0 = (tb & 15) * 32, r0 = (tb >> 4) * 32;
        int tx = tid & 31, ty = tid >> 5;
#pragma unroll
        for (int i = 0; i < 4; i++)
            tile[ty + i * 8][tx] = W[(size_t)(r0 + ty + i * 8) * DMODEL + c0 + tx];
        __syncthreads();
#pragma unroll
        for (int i = 0; i < 4; i++)
            Wt[(size_t)(c0 + ty + i * 8) * DMODEL + r0 + tx] = f2bf(tile[tx][ty + i * 8]);
    } else {
        int ks = (bid - 528) * 8;
        float s1 = 0.f, s2 = 0.f;
#pragma unroll
        for (int kk = 0; kk < 8; kk++) {
            float bpv = bp[ks + kk];
            s1 += bpv * Wq[(size_t)(ks + kk) * DMODEL + tid];
            s2 += bpv * Wq[(size_t)(ks + kk) * DMODEL + tid + 256];
        }
        atomicAdd(&bcomb[tid], s1);
        atomicAdd(&bcomb[tid + 256], s2);
    }
}

// ---------------- K, V (fragment-major), Q projections + histogram: ONE dispatch ----------------
// b 0..63: K; 64..127: V; 128..383: Q (bias = bcomb + b_q); 384..511: histogram.
__global__ __launch_bounds__(256) void k_gemm_all(
    const float* __restrict__ kb, const u16* __restrict__ Wkt, const float* __restrict__ bk,
    u16* __restrict__ Kp,
    const float* __restrict__ vb, const u16* __restrict__ Wvt, const float* __restrict__ bv,
    u16* __restrict__ Vp,
    const float* __restrict__ x, const u16* __restrict__ WcombT,
    const float* __restrict__ bcomb, const float* __restrict__ bq_, u16* __restrict__ Qm,
    const int* __restrict__ cidx, int* __restrict__ counts)
{
    int b = blockIdx.x;
    if (b < 64)
        gemm_bt_body<1, 0, 2>(kb, Wkt, bk, nullptr, Kp, NC, DMODEL, DMODEL, b & 3, b >> 2);
    else if (b < 128)
        gemm_bt_body<1, 0, 1>(vb, Wvt, bv, nullptr, Vp, NC, DMODEL, DMODEL, (b - 64) & 3, (b - 64) >> 2);
    else if (b < 384)
        gemm_bt_body<1, 0, 0>(x, WcombT, bcomb, bq_, Qm, NQ, DMODEL, DMODEL, (b - 128) & 3, (b - 128) >> 2);
    else {
        for (int i = (b - 384) * 256 + threadIdx.x; i < NIDX; i += 128 * 256)
            atomicAdd(&counts[cidx[i]], 1);
    }
}

// ---------------- fused attention + LayerNorm (fragment-major K/V) ----------------
// grid(NQ/32); block 512 = 8 waves = 8 heads. Wave: 32 q, one head, all 2048 c.
// R12's proven 69 us kernel (fragment-major K/V, fixed-shift softmax, fused LN).
__global__ __launch_bounds__(512, 2) void k_attn8(
    const u16* __restrict__ Q, const u16* __restrict__ Kp, const u16* __restrict__ Vp,
    const int* __restrict__ counts, const float* __restrict__ ln_g,
    const float* __restrict__ ln_b, float* __restrict__ Out, float scale2)
{
    __shared__ float sbias[NC];          // 8 KB, log2(count) - 16
    __shared__ unsigned sO[32 * 256];    // 32 KB, swizzled packed O

    int tid = threadIdx.x;
    int lane = tid & 63, wid = tid >> 6;
    int h = wid;
    int ql = lane & 31, hi = lane >> 5;
    int q0 = blockIdx.x * 32;
    int hbase = h * DH;

#pragma unroll
    for (int i = 0; i < 4; i++)
        sbias[tid + i * 512] = log2f((float)counts[tid + i * 512]) - 16.0f;

    bf16x8 qf[4];
#pragma unroll
    for (int m = 0; m < 4; m++)
        qf[m] = *(const bf16x8*)(Q + (size_t)(q0 + ql) * DMODEL + hbase + m * 16 + hi * 8);

    const u16* klane = Kp + (size_t)h * 131072 + hi * 256 + ql * 8;
    const u16* vlane = Vp + (size_t)h * 131072 + hi * 512 + ql * 8;

    bf16x8 kf0[4], kf1[4], vf0[4], vf1[4];
#pragma unroll
    for (int m = 0; m < 4; m++)
        kf0[m] = *(const bf16x8*)(klane + m * 512);
#pragma unroll
    for (int T = 0; T < 2; T++)
#pragma unroll
        for (int ss = 0; ss < 2; ss++)
            vf0[T * 2 + ss] = *(const bf16x8*)(vlane + ss * 1024 + T * 256);

    f32x16 o0 = {}, o1 = {};
    float l_part = 0.f;

    __syncthreads();   // sbias ready

    auto body = [&](int t, bf16x8 (&kfc)[4], bf16x8 (&vfc)[4],
                    bf16x8 (&kfn)[4], bf16x8 (&vfn)[4]) {
        f32x4 bq[4];
#pragma unroll
        for (int j = 0; j < 4; j++)
            bq[j] = *(const f32x4*)(sbias + t * 32 + 8 * j + 4 * hi);

        // QK^T on current K frags
        f32x16 acc = {};
        __builtin_amdgcn_s_setprio(1);
#pragma unroll
        for (int m = 0; m < 4; m++)
            acc = __builtin_amdgcn_mfma_f32_32x32x16_bf16(kfc[m], qf[m], acc, 0, 0, 0);
        __builtin_amdgcn_s_setprio(0);

        // issue next K loads (t=63 -> padded ws)
        const u16* kp = klane + (size_t)(t + 1) * 2048;
#pragma unroll
        for (int m = 0; m < 4; m++)
            kfn[m] = *(const bf16x8*)(kp + m * 512);

        // softmax (fixed shift -16) + pack
        unsigned u[8];
        float rs0 = 0.f, rs1 = 0.f;
#pragma unroll
        for (int j = 0; j < 8; j++) {
            float p0 = exp2f(acc[2 * j] * scale2 + bq[(2 * j) >> 2][(2 * j) & 3]);
            float p1 = exp2f(acc[2 * j + 1] * scale2 + bq[(2 * j + 1) >> 2][(2 * j + 1) & 3]);
            rs0 += p0; rs1 += p1;
            u[j] = pk2(p0, p1);
        }
        l_part += rs0 + rs1;

        plswap(u[0], u[2]); plswap(u[1], u[3]);
        plswap(u[4], u[6]); plswap(u[5], u[7]);
        bf16x8 pb0 = __builtin_bit_cast(bf16x8, *(uint4*)&u[0]);
        bf16x8 pb1 = __builtin_bit_cast(bf16x8, *(uint4*)&u[4]);

        // PV on current V frags
        __builtin_amdgcn_s_setprio(1);
        o0 = __builtin_amdgcn_mfma_f32_32x32x16_bf16(vfc[0], pb0, o0, 0, 0, 0);
        o0 = __builtin_amdgcn_mfma_f32_32x32x16_bf16(vfc[1], pb1, o0, 0, 0, 0);
        o1 = __builtin_amdgcn_mfma_f32_32x32x16_bf16(vfc[2], pb0, o1, 0, 0, 0);
        o1 = __builtin_amdgcn_mfma_f32_32x32x16_bf16(vfc[3], pb1, o1, 0, 0, 0);
        __builtin_amdgcn_s_setprio(0);

        // issue next V loads
        const u16* vp = vlane + (size_t)(t + 1) * 2048;
#pragma unroll
        for (int T = 0; T < 2; T++)
#pragma unroll
            for (int ss = 0; ss < 2; ss++)
                vfn[T * 2 + ss] = *(const bf16x8*)(vp + ss * 1024 + T * 256);
    };

    for (int t = 0; t < NC / 32; t += 2) {
        body(t,     kf0, vf0, kf1, vf1);
        body(t + 1, kf1, vf1, kf0, vf0);
    }

    float l_tot = l_part + __shfl_xor(l_part, 32);
    float inv = 1.0f / l_tot;

#pragma unroll
    for (int T = 0; T < 2; T++)
#pragma unroll
        for (int j = 0; j < 8; j++) {
            int dw = T * 16 + (j & 1) + 4 * (j >> 1) + 2 * hi;
            float a = (T == 0) ? o0[2 * j] : o1[2 * j];
            float b = (T == 0) ? o0[2 * j + 1] : o1[2 * j + 1];
            sO[soff(ql, h * 32 + dw)] = pk2(a * inv, b * inv);
        }
    __syncthreads();

    float4 g0 = *(const float4*)(ln_g + lane * 8);
    float4 g1 = *(const float4*)(ln_g + lane * 8 + 4);
    float4 b0 = *(const float4*)(ln_b + lane * 8);
    float4 b1 = *(const float4*)(ln_b + lane * 8 + 4);
#pragma unroll
    for (int rr = 0; rr < 4; rr++) {
        int r = wid * 4 + rr;
        uint4 pw = *(const uint4*)(&sO[r * 256 + ((lane ^ (r & 7)) << 2)]);
        float v[8];
        v[0] = bf2f((u16)(pw.x & 0xffff)); v[1] = bf2f((u16)(pw.x >> 16));
        v[2] = bf2f((u16)(pw.y & 0xffff)); v[3] = bf2f((u16)(pw.y >> 16));
        v[4] = bf2f((u16)(pw.z & 0xffff)); v[5] = bf2f((u16)(pw.z >> 16));
        v[6] = bf2f((u16)(pw.w & 0xffff)); v[7] = bf2f((u16)(pw.w >> 16));
        float sum = 0.f, sq = 0.f;
#pragma unroll
        for (int j = 0; j < 8; j++) { sum += v[j]; sq += v[j] * v[j]; }
#pragma unroll
        for (int msk = 1; msk <= 32; msk <<= 1) { sum += __shfl_xor(sum, msk); sq += __shfl_xor(sq, msk); }
        float mu = sum * (1.f / DMODEL);
        float var = sq * (1.f / DMODEL) - mu * mu;
        float rstd = rsqrtf(var + 1e-5f);
        float o[8];
        o[0] = (v[0] - mu) * rstd * g0.x + b0.x; o[1] = (v[1] - mu) * rstd * g0.y + b0.y;
        o[2] = (v[2] - mu) * rstd * g0.z + b0.z; o[3] = (v[3] - mu) * rstd * g0.w + b0.w;
        o[4] = (v[4] - mu) * rstd * g1.x + b1.x; o[5] = (v[5] - mu) * rstd * g1.y + b1.y;
        o[6] = (v[6] - mu) * rstd * g1.z + b1.z; o[7] = (v[7] - mu) * rstd * g1.w + b1.w;
        float* op = Out + (size_t)(q0 + r) * DMODEL + lane * 8;
        *(float4*)op = *(float4*)&o[0];
        *(float4*)(op + 4) = *(float4*)&o[4];
    }
}

extern "C" void kernel_launch(void* const* d_in, const int* in_sizes, int n_in,
                              void* d_out, int out_size, void* d_ws, size_t ws_size,
                              hipStream_t stream)
{
    const float* x      = (const float*)d_in[0];
    const float* W_proj = (const float*)d_in[1];
    const float* b_proj = (const float*)d_in[2];
    const float* W_q    = (const float*)d_in[3];
    const float* b_q    = (const float*)d_in[4];
    const float* W_k    = (const float*)d_in[5];
    const float* b_k    = (const float*)d_in[6];
    const float* W_v    = (const float*)d_in[7];
    const float* b_v    = (const float*)d_in[8];
    const float* k_buf  = (const float*)d_in[9];
    const float* v_buf  = (const float*)d_in[10];
    const float* ln_g   = (const float*)d_in[11];
    const float* ln_b   = (const float*)d_in[12];
    const int*   c_idx  = (const int*)d_in[13];
    float* out = (float*)d_out;

    char* ws = (char*)d_ws;
    size_t off = 0;
    auto alloc = [&](size_t bytes) -> void* {
        void* p = ws + off;
        off += (bytes + 255) & ~(size_t)255;
        return p;
    };
    u16* Wk_t   = (u16*)alloc((size_t)DMODEL * DMODEL * 2);
    u16* Wv_t   = (u16*)alloc((size_t)DMODEL * DMODEL * 2);
    u16* WcombT = (u16*)alloc((size_t)DMODEL * DMODEL * 2);
    u16* Qm     = (u16*)alloc((size_t)NQ * DMODEL * 2);
    u16* Kpm    = (u16*)alloc((size_t)NC * DMODEL * 2);
    u16* Vpm    = (u16*)alloc((size_t)DMODEL * NC * 2);
    int*   counts = (int*)alloc(NC * 4);       // contiguous with bcomb: one memset
    float* bcomb  = (float*)alloc(DMODEL * 4);
    (void)alloc(2200000);   // pad: wrap-free tail prefetch reads past Kpm/Vpm

    hipMemsetAsync(counts, 0, NC * 4 + 256 + DMODEL * 4, stream);  // counts + pad + bcomb

    k_prep2<<<dim3(592), dim3(256), 0, stream>>>(
        W_q, W_k, W_v, W_proj, b_proj,
        Wk_t, Wv_t, WcombT, bcomb);

    k_gemm_all<<<dim3(512), dim3(256), 0, stream>>>(
        k_buf, Wk_t, b_k, Kpm,
        v_buf, Wv_t, b_v, Vpm,
        x, WcombT, bcomb, b_q, Qm,
        c_idx, counts);

    // scale2 = (1/sqrt(512)) * log2(e); fixed shift folded into sbias
    k_attn8<<<dim3(NQ / 32), dim3(512), 0, stream>>>(Qm, Kpm, Vpm, counts, ln_g, ln_b, out, 0.06375872f);
    (void)in_sizes; (void)n_in; (void)out_size; (void)ws_size;
}

// Round 17
// 125.104 us; speedup vs baseline: 1.0612x; 1.0612x over previous
//
#include <hip/hip_runtime.h>
#include <math.h>

typedef __bf16 bf16x8 __attribute__((ext_vector_type(8)));
typedef __bf16 bf16x2 __attribute__((ext_vector_type(2)));
typedef float f32x4 __attribute__((ext_vector_type(4)));
typedef float f32x16 __attribute__((ext_vector_type(16)));
typedef unsigned u32x2v __attribute__((ext_vector_type(2)));
typedef unsigned short u16;

#define NQ 8192
#define DMODEL 512
#define NHEAD 8
#define DH 64
#define NC 2048
#define NIDX 100000

__device__ __forceinline__ u16 f2bf(float f) {
    unsigned u = __float_as_uint(f);
    u += 0x7fffu + ((u >> 16) & 1u);
    return (u16)(u >> 16);
}
__device__ __forceinline__ float bf2f(u16 h) {
    return __uint_as_float(((unsigned)h) << 16);
}
__device__ __forceinline__ unsigned pk2(float a, float b) {
    bf16x2 t; t[0] = (__bf16)a; t[1] = (__bf16)b;   // v_cvt_pk_bf16_f32 (RNE)
    return __builtin_bit_cast(unsigned, t);
}
__device__ __forceinline__ void plswap(unsigned& a, unsigned& b) {
    u32x2v r = __builtin_amdgcn_permlane32_swap(a, b, false, false);
    a = r[0]; b = r[1];
}
// swizzled u32 index into sO[32][256]: 16B-block XOR by row
__device__ __forceinline__ int soff(int q, int col) {
    return q * 256 + ((((col >> 2) ^ (q & 7)) << 2) | (col & 3));
}

// ---------------- bf16 GEMM core: C = A[M][K] * Bt[N][K]^T + bias[N] (+bias_b) --------
// A_MODE: 0 = bf16 row-major; 1 = f32 row-major (cvt during staging);
//         2 = f32 TRANSPOSED source (A[i][k] = src[k*M + i]).
// B_MODE: 0 = bf16 row-major; 1 = f32 row-major.
// OUT_T : 0 = row-major [M][N]; 1 = V fragment-major; 2 = K fragment-major.
template <int A_MODE, int B_MODE, int OUT_T>
__device__ __forceinline__ void gemm_bt_body(
    const void* __restrict__ A_, const void* __restrict__ Bt_,
    const float* __restrict__ bias, const float* __restrict__ bias_b,
    u16* __restrict__ Cmat, int M, int N, int K, int bx, int by)
{
    constexpr int LDP = 40;
    __shared__ __align__(16) u16 As[128 * LDP];
    __shared__ __align__(16) u16 Bs[128 * LDP];
    int tid = threadIdx.x;
    int lane = tid & 63, wid = tid >> 6;
    int wrow = (wid >> 1) * 64, wcol = (wid & 1) * 64;
    int m0 = by * 128, n0 = bx * 128;
    int lr = lane & 15, lg = lane >> 4;
    f32x4 acc[4][4] = {};

    for (int k0 = 0; k0 < K; k0 += 32) {
#pragma unroll
        for (int c = 0; c < 2; c++) {
            int ch = tid + c * 256;
            int row = ch >> 2, colc = (ch & 3) * 8;
            uint4 av;
            if (A_MODE == 1) {
                const float* Af = (const float*)A_;
                float4 a0 = *(const float4*)(Af + (size_t)(m0 + row) * K + k0 + colc);
                float4 a1 = *(const float4*)(Af + (size_t)(m0 + row) * K + k0 + colc + 4);
                av.x = pk2(a0.x, a0.y); av.y = pk2(a0.z, a0.w);
                av.z = pk2(a1.x, a1.y); av.w = pk2(a1.z, a1.w);
            } else if (A_MODE == 2) {
                const float* Af = (const float*)A_;
                float e[8];
#pragma unroll
                for (int i = 0; i < 8; i++)
                    e[i] = Af[(size_t)(k0 + colc + i) * M + m0 + row];
                av.x = pk2(e[0], e[1]); av.y = pk2(e[2], e[3]);
                av.z = pk2(e[4], e[5]); av.w = pk2(e[6], e[7]);
            } else {
                av = *(const uint4*)((const u16*)A_ + (size_t)(m0 + row) * K + k0 + colc);
            }
            *(uint4*)(&As[row * LDP + colc]) = av;
            uint4 bv;
            if (B_MODE == 1) {
                const float* Bf = (const float*)Bt_;
                float4 b0 = *(const float4*)(Bf + (size_t)(n0 + row) * K + k0 + colc);
                float4 b1 = *(const float4*)(Bf + (size_t)(n0 + row) * K + k0 + colc + 4);
                bv.x = pk2(b0.x, b0.y); bv.y = pk2(b0.z, b0.w);
                bv.z = pk2(b1.x, b1.y); bv.w = pk2(b1.z, b1.w);
            } else {
                bv = *(const uint4*)((const u16*)Bt_ + (size_t)(n0 + row) * K + k0 + colc);
            }
            *(uint4*)(&Bs[row * LDP + colc]) = bv;
        }
        __syncthreads();
        bf16x8 af[4], bfr[4];
#pragma unroll
        for (int m = 0; m < 4; m++)
            af[m] = *(const bf16x8*)(&As[(wrow + m * 16 + lr) * LDP + lg * 8]);
#pragma unroll
        for (int n = 0; n < 4; n++)
            bfr[n] = *(const bf16x8*)(&Bs[(wcol + n * 16 + lr) * LDP + lg * 8]);
#pragma unroll
        for (int m = 0; m < 4; m++)
#pragma unroll
            for (int n = 0; n < 4; n++)
                acc[m][n] = __builtin_amdgcn_mfma_f32_16x16x32_bf16(af[m], bfr[n], acc[m][n], 0, 0, 0);
        __syncthreads();
    }
#pragma unroll
    for (int n = 0; n < 4; n++) {
        int col = n0 + wcol + n * 16 + lr;
        float bv = (bias ? bias[col] : 0.0f) + (bias_b ? bias_b[col] : 0.0f);
#pragma unroll
        for (int m = 0; m < 4; m++) {
            int rbase = m0 + wrow + m * 16 + lg * 4;
            if (OUT_T == 1) {
                int hh = col >> 6, T = (col >> 5) & 1, ql = col & 31;
                int t = rbase >> 5, cc = rbase & 31;
                int u = ((cc >> 4) * 2 + ((cc >> 3) & 1)) * 2 + T;
                size_t off = (size_t)hh * 131072 + (size_t)t * 2048 + u * 256 + ql * 8 + (cc & 7);
                ushort4 o4;
                o4.x = f2bf(acc[m][n][0] + bv);
                o4.y = f2bf(acc[m][n][1] + bv);
                o4.z = f2bf(acc[m][n][2] + bv);
                o4.w = f2bf(acc[m][n][3] + bv);
                *(ushort4*)(Cmat + off) = o4;
            } else if (OUT_T == 2) {
                int hh = col >> 6, m2 = (col >> 4) & 3, h2 = (col >> 3) & 1, jj = col & 7;
                size_t ub = (size_t)hh * 131072 + (size_t)(m2 * 2 + h2) * 256 + jj;
#pragma unroll
                for (int r = 0; r < 4; r++) {
                    int c = rbase + r;
                    Cmat[ub + (size_t)(c >> 5) * 2048 + (c & 31) * 8] = f2bf(acc[m][n][r] + bv);
                }
            } else {
#pragma unroll
                for (int r = 0; r < 4; r++)
                    Cmat[(size_t)(rbase + r) * N + col] = f2bf(acc[m][n][r] + bv);
            }
        }
    }
}

// ---------------- prep: WcombT GEMM + Wk/Wv transposes + bcomb + x->bf16 ----------------
// bid 0..15    : WcombT = Wq^T @ Wp^T  (A_MODE=2, R15-proven)
// bid 16..527  : Wk^T (16..271), Wv^T (272..527)
// bid 528..591 : bcomb partial sums (atomicAdd; bcomb pre-zeroed)
// bid 592..1103: x f32 -> bf16 (512 blocks, 32 elems/thread)
__global__ __launch_bounds__(256) void k_prep2(
    const float* __restrict__ Wq, const float* __restrict__ Wk, const float* __restrict__ Wv,
    const float* __restrict__ Wp, const float* __restrict__ bp, const float* __restrict__ x,
    u16* __restrict__ Wk_t, u16* __restrict__ Wv_t,
    u16* __restrict__ WcombT, float* __restrict__ bcomb, u16* __restrict__ x_bf)
{
    __shared__ float tile[32][33];
    int bid = blockIdx.x, tid = threadIdx.x;
    if (bid < 16) {
        gemm_bt_body<2, 1, 0>(Wq, Wp, nullptr, nullptr, WcombT, DMODEL, DMODEL, DMODEL,
                              bid & 3, bid >> 2);
    } else if (bid < 528) {
        const float* W; u16* Wt; int tb;
        if (bid < 272) { W = Wk; Wt = Wk_t; tb = bid - 16; }
        else           { W = Wv; Wt = Wv_t; tb = bid - 272; }
        int c0 = (tb & 15) * 32, r0 = (tb >> 4) * 32;
        int tx = tid & 31, ty = tid >> 5;
#pragma unroll
        for (int i = 0; i < 4; i++)
            tile[ty + i * 8][tx] = W[(size_t)(r0 + ty + i * 8) * DMODEL + c0 + tx];
        __syncthreads();
#pragma unroll
        for (int i = 0; i < 4; i++)
            Wt[(size_t)(c0 + ty + i * 8) * DMODEL + r0 + tx] = f2bf(tile[tx][ty + i * 8]);
    } else if (bid < 592) {
        int ks = (bid - 528) * 8;
        float s1 = 0.f, s2 = 0.f;
#pragma unroll
        for (int kk = 0; kk < 8; kk++) {
            float bpv = bp[ks + kk];
            s1 += bpv * Wq[(size_t)(ks + kk) * DMODEL + tid];
            s2 += bpv * Wq[(size_t)(ks + kk) * DMODEL + tid + 256];
        }
        atomicAdd(&bcomb[tid], s1);
        atomicAdd(&bcomb[tid + 256], s2);
    } else {
        // x -> bf16: 512 blocks x 256 threads x 32 elems
        size_t base = (size_t)(bid - 592) * 8192 + tid * 8;
#pragma unroll
        for (int i = 0; i < 4; i++) {
            size_t e = base + (size_t)i * 2048;
            float4 a0 = *(const float4*)(x + e);
            float4 a1 = *(const float4*)(x + e + 4);
            uint4 o;
            o.x = pk2(a0.x, a0.y); o.y = pk2(a0.z, a0.w);
            o.z = pk2(a1.x, a1.y); o.w = pk2(a1.z, a1.w);
            *(uint4*)(x_bf + e) = o;
        }
    }
}

// ---------------- K, V (fragment-major), Q projections + histogram: ONE dispatch ----------------
// b 0..63: K; 64..127: V; 128..383: Q (bf16 x, bias = bcomb + b_q); 384..511: histogram.
__global__ __launch_bounds__(256) void k_gemm_all(
    const float* __restrict__ kb, const u16* __restrict__ Wkt, const float* __restrict__ bk,
    u16* __restrict__ Kp,
    const float* __restrict__ vb, const u16* __restrict__ Wvt, const float* __restrict__ bv,
    u16* __restrict__ Vp,
    const u16* __restrict__ x_bf, const u16* __restrict__ WcombT,
    const float* __restrict__ bcomb, const float* __restrict__ bq_, u16* __restrict__ Qm,
    const int* __restrict__ cidx, int* __restrict__ counts)
{
    int b = blockIdx.x;
    if (b < 64)
        gemm_bt_body<1, 0, 2>(kb, Wkt, bk, nullptr, Kp, NC, DMODEL, DMODEL, b & 3, b >> 2);
    else if (b < 128)
        gemm_bt_body<1, 0, 1>(vb, Wvt, bv, nullptr, Vp, NC, DMODEL, DMODEL, (b - 64) & 3, (b - 64) >> 2);
    else if (b < 384)
        gemm_bt_body<0, 0, 0>(x_bf, WcombT, bcomb, bq_, Qm, NQ, DMODEL, DMODEL, (b - 128) & 3, (b - 128) >> 2);
    else {
        for (int i = (b - 384) * 256 + threadIdx.x; i < NIDX; i += 128 * 256)
            atomicAdd(&counts[cidx[i]], 1);
    }
}

// ---------------- fused attention + LayerNorm (fragment-major K/V) ----------------
// grid(NQ/32); block 512 = 8 waves = 8 heads. Wave: 32 q, one head, all 2048 c.
// R12's proven 69 us kernel (fragment-major K/V, fixed-shift softmax, fused LN).
__global__ __launch_bounds__(512, 2) void k_attn8(
    const u16* __restrict__ Q, const u16* __restrict__ Kp, const u16* __restrict__ Vp,
    const int* __restrict__ counts, const float* __restrict__ ln_g,
    const float* __restrict__ ln_b, float* __restrict__ Out, float scale2)
{
    __shared__ float sbias[NC];          // 8 KB, log2(count) - 16
    __shared__ unsigned sO[32 * 256];    // 32 KB, swizzled packed O

    int tid = threadIdx.x;
    int lane = tid & 63, wid = tid >> 6;
    int h = wid;
    int ql = lane & 31, hi = lane >> 5;
    int q0 = blockIdx.x * 32;
    int hbase = h * DH;

#pragma unroll
    for (int i = 0; i < 4; i++)
        sbias[tid + i * 512] = log2f((float)counts[tid + i * 512]) - 16.0f;

    bf16x8 qf[4];
#pragma unroll
    for (int m = 0; m < 4; m++)
        qf[m] = *(const bf16x8*)(Q + (size_t)(q0 + ql) * DMODEL + hbase + m * 16 + hi * 8);

    const u16* klane = Kp + (size_t)h * 131072 + hi * 256 + ql * 8;
    const u16* vlane = Vp + (size_t)h * 131072 + hi * 512 + ql * 8;

    bf16x8 kf0[4], kf1[4], vf0[4], vf1[4];
#pragma unroll
    for (int m = 0; m < 4; m++)
        kf0[m] = *(const bf16x8*)(klane + m * 512);
#pragma unroll
    for (int T = 0; T < 2; T++)
#pragma unroll
        for (int ss = 0; ss < 2; ss++)
            vf0[T * 2 + ss] = *(const bf16x8*)(vlane + ss * 1024 + T * 256);

    f32x16 o0 = {}, o1 = {};
    float l_part = 0.f;

    __syncthreads();   // sbias ready

    auto body = [&](int t, bf16x8 (&kfc)[4], bf16x8 (&vfc)[4],
                    bf16x8 (&kfn)[4], bf16x8 (&vfn)[4]) {
        f32x4 bq[4];
#pragma unroll
        for (int j = 0; j < 4; j++)
            bq[j] = *(const f32x4*)(sbias + t * 32 + 8 * j + 4 * hi);

        // QK^T on current K frags
        f32x16 acc = {};
        __builtin_amdgcn_s_setprio(1);
#pragma unroll
        for (int m = 0; m < 4; m++)
            acc = __builtin_amdgcn_mfma_f32_32x32x16_bf16(kfc[m], qf[m], acc, 0, 0, 0);
        __builtin_amdgcn_s_setprio(0);

        // issue next K loads (t=63 -> padded ws)
        const u16* kp = klane + (size_t)(t + 1) * 2048;
#pragma unroll
        for (int m = 0; m < 4; m++)
            kfn[m] = *(const bf16x8*)(kp + m * 512);

        // softmax (fixed shift -16) + pack
        unsigned u[8];
        float rs0 = 0.f, rs1 = 0.f;
#pragma unroll
        for (int j = 0; j < 8; j++) {
            float p0 = exp2f(acc[2 * j] * scale2 + bq[(2 * j) >> 2][(2 * j) & 3]);
            float p1 = exp2f(acc[2 * j + 1] * scale2 + bq[(2 * j + 1) >> 2][(2 * j + 1) & 3]);
            rs0 += p0; rs1 += p1;
            u[j] = pk2(p0, p1);
        }
        l_part += rs0 + rs1;

        plswap(u[0], u[2]); plswap(u[1], u[3]);
        plswap(u[4], u[6]); plswap(u[5], u[7]);
        bf16x8 pb0 = __builtin_bit_cast(bf16x8, *(uint4*)&u[0]);
        bf16x8 pb1 = __builtin_bit_cast(bf16x8, *(uint4*)&u[4]);

        // PV on current V frags
        __builtin_amdgcn_s_setprio(1);
        o0 = __builtin_amdgcn_mfma_f32_32x32x16_bf16(vfc[0], pb0, o0, 0, 0, 0);
        o0 = __builtin_amdgcn_mfma_f32_32x32x16_bf16(vfc[1], pb1, o0, 0, 0, 0);
        o1 = __builtin_amdgcn_mfma_f32_32x32x16_bf16(vfc[2], pb0, o1, 0, 0, 0);
        o1 = __builtin_amdgcn_mfma_f32_32x32x16_bf16(vfc[3], pb1, o1, 0, 0, 0);
        __builtin_amdgcn_s_setprio(0);

        // issue next V loads
        const u16* vp = vlane + (size_t)(t + 1) * 2048;
#pragma unroll
        for (int T = 0; T < 2; T++)
#pragma unroll
            for (int ss = 0; ss < 2; ss++)
                vfn[T * 2 + ss] = *(const bf16x8*)(vp + ss * 1024 + T * 256);
    };

    for (int t = 0; t < NC / 32; t += 2) {
        body(t,     kf0, vf0, kf1, vf1);
        body(t + 1, kf1, vf1, kf0, vf0);
    }

    float l_tot = l_part + __shfl_xor(l_part, 32);
    float inv = 1.0f / l_tot;

#pragma unroll
    for (int T = 0; T < 2; T++)
#pragma unroll
        for (int j = 0; j < 8; j++) {
            int dw = T * 16 + (j & 1) + 4 * (j >> 1) + 2 * hi;
            float a = (T == 0) ? o0[2 * j] : o1[2 * j];
            float b = (T == 0) ? o0[2 * j + 1] : o1[2 * j + 1];
            sO[soff(ql, h * 32 + dw)] = pk2(a * inv, b * inv);
        }
    __syncthreads();

    float4 g0 = *(const float4*)(ln_g + lane * 8);
    float4 g1 = *(const float4*)(ln_g + lane * 8 + 4);
    float4 b0 = *(const float4*)(ln_b + lane * 8);
    float4 b1 = *(const float4*)(ln_b + lane * 8 + 4);
#pragma unroll
    for (int rr = 0; rr < 4; rr++) {
        int r = wid * 4 + rr;
        uint4 pw = *(const uint4*)(&sO[r * 256 + ((lane ^ (r & 7)) << 2)]);
        float v[8];
        v[0] = bf2f((u16)(pw.x & 0xffff)); v[1] = bf2f((u16)(pw.x >> 16));
        v[2] = bf2f((u16)(pw.y & 0xffff)); v[3] = bf2f((u16)(pw.y >> 16));
        v[4] = bf2f((u16)(pw.z & 0xffff)); v[5] = bf2f((u16)(pw.z >> 16));
        v[6] = bf2f((u16)(pw.w & 0xffff)); v[7] = bf2f((u16)(pw.w >> 16));
        float sum = 0.f, sq = 0.f;
#pragma unroll
        for (int j = 0; j < 8; j++) { sum += v[j]; sq += v[j] * v[j]; }
#pragma unroll
        for (int msk = 1; msk <= 32; msk <<= 1) { sum += __shfl_xor(sum, msk); sq += __shfl_xor(sq, msk); }
        float mu = sum * (1.f / DMODEL);
        float var = sq * (1.f / DMODEL) - mu * mu;
        float rstd = rsqrtf(var + 1e-5f);
        float o[8];
        o[0] = (v[0] - mu) * rstd * g0.x + b0.x; o[1] = (v[1] - mu) * rstd * g0.y + b0.y;
        o[2] = (v[2] - mu) * rstd * g0.z + b0.z; o[3] = (v[3] - mu) * rstd * g0.w + b0.w;
        o[4] = (v[4] - mu) * rstd * g1.x + b1.x; o[5] = (v[5] - mu) * rstd * g1.y + b1.y;
        o[6] = (v[6] - mu) * rstd * g1.z + b1.z; o[7] = (v[7] - mu) * rstd * g1.w + b1.w;
        float* op = Out + (size_t)(q0 + r) * DMODEL + lane * 8;
        *(float4*)op = *(float4*)&o[0];
        *(float4*)(op + 4) = *(float4*)&o[4];
    }
}

extern "C" void kernel_launch(void* const* d_in, const int* in_sizes, int n_in,
                              void* d_out, int out_size, void* d_ws, size_t ws_size,
                              hipStream_t stream)
{
    const float* x      = (const float*)d_in[0];
    const float* W_proj = (const float*)d_in[1];
    const float* b_proj = (const float*)d_in[2];
    const float* W_q    = (const float*)d_in[3];
    const float* b_q    = (const float*)d_in[4];
    const float* W_k    = (const float*)d_in[5];
    const float* b_k    = (const float*)d_in[6];
    const float* W_v    = (const float*)d_in[7];
    const float* b_v    = (const float*)d_in[8];
    const float* k_buf  = (const float*)d_in[9];
    const float* v_buf  = (const float*)d_in[10];
    const float* ln_g   = (const float*)d_in[11];
    const float* ln_b   = (const float*)d_in[12];
    const int*   c_idx  = (const int*)d_in[13];
    float* out = (float*)d_out;

    char* ws = (char*)d_ws;
    size_t off = 0;
    auto alloc = [&](size_t bytes) -> void* {
        void* p = ws + off;
        off += (bytes + 255) & ~(size_t)255;
        return p;
    };
    u16* Wk_t   = (u16*)alloc((size_t)DMODEL * DMODEL * 2);
    u16* Wv_t   = (u16*)alloc((size_t)DMODEL * DMODEL * 2);
    u16* WcombT = (u16*)alloc((size_t)DMODEL * DMODEL * 2);
    u16* Qm     = (u16*)alloc((size_t)NQ * DMODEL * 2);
    u16* Kpm    = (u16*)alloc((size_t)NC * DMODEL * 2);
    u16* Vpm    = (u16*)alloc((size_t)DMODEL * NC * 2);
    int*   counts = (int*)alloc(NC * 4);       // contiguous with bcomb: one memset
    float* bcomb  = (float*)alloc(DMODEL * 4);
    u16* x_bf   = (u16*)alloc((size_t)NQ * DMODEL * 2);
    (void)alloc(2200000);   // pad: wrap-free tail prefetch reads past Kpm/Vpm

    hipMemsetAsync(counts, 0, NC * 4 + 256 + DMODEL * 4, stream);  // counts + pad + bcomb

    k_prep2<<<dim3(1104), dim3(256), 0, stream>>>(
        W_q, W_k, W_v, W_proj, b_proj, x,
        Wk_t, Wv_t, WcombT, bcomb, x_bf);

    k_gemm_all<<<dim3(512), dim3(256), 0, stream>>>(
        k_buf, Wk_t, b_k, Kpm,
        v_buf, Wv_t, b_v, Vpm,
        x_bf, WcombT, bcomb, b_q, Qm,
        c_idx, counts);

    // scale2 = (1/sqrt(512)) * log2(e); fixed shift folded into sbias
    k_attn8<<<dim3(NQ / 32), dim3(512), 0, stream>>>(Qm, Kpm, Vpm, counts, ln_g, ln_b, out, 0.06375872f);
    (void)in_sizes; (void)n_in; (void)out_size; (void)ws_size;
}

// Round 18
// 119.840 us; speedup vs baseline: 1.1078x; 1.0439x over previous
//
#include <hip/hip_runtime.h>
#include <math.h>

typedef __bf16 bf16x8 __attribute__((ext_vector_type(8)));
typedef __bf16 bf16x2 __attribute__((ext_vector_type(2)));
typedef float f32x4 __attribute__((ext_vector_type(4)));
typedef float f32x16 __attribute__((ext_vector_type(16)));
typedef unsigned u32x2v __attribute__((ext_vector_type(2)));
typedef unsigned short u16;
typedef long long i64;
typedef unsigned char u8;

#define NQ 8192
#define DMODEL 512
#define NHEAD 8
#define DH 64
#define NC 2048
#define NIDX 100000

__device__ __forceinline__ u16 f2bf(float f) {
    unsigned u = __float_as_uint(f);
    u += 0x7fffu + ((u >> 16) & 1u);
    return (u16)(u >> 16);
}
__device__ __forceinline__ float bf2f(u16 h) {
    return __uint_as_float(((unsigned)h) << 16);
}
__device__ __forceinline__ unsigned pk2(float a, float b) {
    bf16x2 t; t[0] = (__bf16)a; t[1] = (__bf16)b;   // v_cvt_pk_bf16_f32 (RNE)
    return __builtin_bit_cast(unsigned, t);
}
__device__ __forceinline__ u8 f2fp8(float f) {     // OCP e4m3 via v_cvt_pk_fp8_f32
    int p = __builtin_amdgcn_cvt_pk_fp8_f32(f, f, 0, false);
    return (u8)(p & 0xff);
}
__device__ __forceinline__ void plswap(unsigned& a, unsigned& b) {
    u32x2v r = __builtin_amdgcn_permlane32_swap(a, b, false, false);
    a = r[0]; b = r[1];
}
// swizzled u32 index into sO[32][256]: 16B-block XOR by row
__device__ __forceinline__ int soff(int q, int col) {
    return q * 256 + ((((col >> 2) ^ (q & 7)) << 2) | (col & 3));
}

// ---------------- bf16 GEMM core: C = A[M][K] * Bt[N][K]^T + bias[N] (+bias_b) --------
// A_MODE: 0 = bf16 row-major; 1 = f32 row-major (cvt during staging);
//         2 = f32 TRANSPOSED source (A[i][k] = src[k*M + i]).
// B_MODE: 0 = bf16 row-major; 1 = f32 row-major.
// OUT_T : 0 = bf16 row-major [M][N]; 1 = V fragment-major bf16;
//         3 = fp8 row-major [M][N];  4 = K fragment-major fp8 (8B units).
template <int A_MODE, int B_MODE, int OUT_T>
__device__ __forceinline__ void gemm_bt_body(
    const void* __restrict__ A_, const void* __restrict__ Bt_,
    const float* __restrict__ bias, const float* __restrict__ bias_b,
    void* __restrict__ Cv, int M, int N, int K, int bx, int by)
{
    constexpr int LDP = 40;
    __shared__ __align__(16) u16 As[128 * LDP];
    __shared__ __align__(16) u16 Bs[128 * LDP];
    int tid = threadIdx.x;
    int lane = tid & 63, wid = tid >> 6;
    int wrow = (wid >> 1) * 64, wcol = (wid & 1) * 64;
    int m0 = by * 128, n0 = bx * 128;
    int lr = lane & 15, lg = lane >> 4;
    f32x4 acc[4][4] = {};

    for (int k0 = 0; k0 < K; k0 += 32) {
#pragma unroll
        for (int c = 0; c < 2; c++) {
            int ch = tid + c * 256;
            int row = ch >> 2, colc = (ch & 3) * 8;
            uint4 av;
            if (A_MODE == 1) {
                const float* Af = (const float*)A_;
                float4 a0 = *(const float4*)(Af + (size_t)(m0 + row) * K + k0 + colc);
                float4 a1 = *(const float4*)(Af + (size_t)(m0 + row) * K + k0 + colc + 4);
                av.x = pk2(a0.x, a0.y); av.y = pk2(a0.z, a0.w);
                av.z = pk2(a1.x, a1.y); av.w = pk2(a1.z, a1.w);
            } else if (A_MODE == 2) {
                const float* Af = (const float*)A_;
                float e[8];
#pragma unroll
                for (int i = 0; i < 8; i++)
                    e[i] = Af[(size_t)(k0 + colc + i) * M + m0 + row];
                av.x = pk2(e[0], e[1]); av.y = pk2(e[2], e[3]);
                av.z = pk2(e[4], e[5]); av.w = pk2(e[6], e[7]);
            } else {
                av = *(const uint4*)((const u16*)A_ + (size_t)(m0 + row) * K + k0 + colc);
            }
            *(uint4*)(&As[row * LDP + colc]) = av;
            uint4 bv;
            if (B_MODE == 1) {
                const float* Bf = (const float*)Bt_;
                float4 b0 = *(const float4*)(Bf + (size_t)(n0 + row) * K + k0 + colc);
                float4 b1 = *(const float4*)(Bf + (size_t)(n0 + row) * K + k0 + colc + 4);
                bv.x = pk2(b0.x, b0.y); bv.y = pk2(b0.z, b0.w);
                bv.z = pk2(b1.x, b1.y); bv.w = pk2(b1.z, b1.w);
            } else {
                bv = *(const uint4*)((const u16*)Bt_ + (size_t)(n0 + row) * K + k0 + colc);
            }
            *(uint4*)(&Bs[row * LDP + colc]) = bv;
        }
        __syncthreads();
        bf16x8 af[4], bfr[4];
#pragma unroll
        for (int m = 0; m < 4; m++)
            af[m] = *(const bf16x8*)(&As[(wrow + m * 16 + lr) * LDP + lg * 8]);
#pragma unroll
        for (int n = 0; n < 4; n++)
            bfr[n] = *(const bf16x8*)(&Bs[(wcol + n * 16 + lr) * LDP + lg * 8]);
#pragma unroll
        for (int m = 0; m < 4; m++)
#pragma unroll
            for (int n = 0; n < 4; n++)
                acc[m][n] = __builtin_amdgcn_mfma_f32_16x16x32_bf16(af[m], bfr[n], acc[m][n], 0, 0, 0);
        __syncthreads();
    }
#pragma unroll
    for (int n = 0; n < 4; n++) {
        int col = n0 + wcol + n * 16 + lr;
        float bv = (bias ? bias[col] : 0.0f) + (bias_b ? bias_b[col] : 0.0f);
#pragma unroll
        for (int m = 0; m < 4; m++) {
            int rbase = m0 + wrow + m * 16 + lg * 4;
            if (OUT_T == 1) {
                u16* Cmat = (u16*)Cv;
                int hh = col >> 6, T = (col >> 5) & 1, ql = col & 31;
                int t = rbase >> 5, cc = rbase & 31;
                int u = ((cc >> 4) * 2 + ((cc >> 3) & 1)) * 2 + T;
                size_t off = (size_t)hh * 131072 + (size_t)t * 2048 + u * 256 + ql * 8 + (cc & 7);
                ushort4 o4;
                o4.x = f2bf(acc[m][n][0] + bv);
                o4.y = f2bf(acc[m][n][1] + bv);
                o4.z = f2bf(acc[m][n][2] + bv);
                o4.w = f2bf(acc[m][n][3] + bv);
                *(ushort4*)(Cmat + off) = o4;
            } else if (OUT_T == 4) {
                u8* Cf8 = (u8*)Cv;
                int hh = col >> 6, m2 = (col >> 4) & 3, h2 = (col >> 3) & 1, jj = col & 7;
                size_t ub = (size_t)hh * 131072 + (size_t)(m2 * 2 + h2) * 256 + jj;
#pragma unroll
                for (int r = 0; r < 4; r++) {
                    int c = rbase + r;
                    Cf8[ub + (size_t)(c >> 5) * 2048 + (c & 31) * 8] = f2fp8(acc[m][n][r] + bv);
                }
            } else if (OUT_T == 3) {
                u8* Cf8 = (u8*)Cv;
#pragma unroll
                for (int r = 0; r < 4; r++)
                    Cf8[(size_t)(rbase + r) * N + col] = f2fp8(acc[m][n][r] + bv);
            } else {
                u16* Cmat = (u16*)Cv;
#pragma unroll
                for (int r = 0; r < 4; r++)
                    Cmat[(size_t)(rbase + r) * N + col] = f2bf(acc[m][n][r] + bv);
            }
        }
    }
}

// ---------------- prep: WcombT GEMM + Wk/Wv transposes + bcomb + x->bf16 ----------------
__global__ __launch_bounds__(256) void k_prep2(
    const float* __restrict__ Wq, const float* __restrict__ Wk, const float* __restrict__ Wv,
    const float* __restrict__ Wp, const float* __restrict__ bp, const float* __restrict__ x,
    u16* __restrict__ Wk_t, u16* __restrict__ Wv_t,
    u16* __restrict__ WcombT, float* __restrict__ bcomb, u16* __restrict__ x_bf)
{
    __shared__ float tile[32][33];
    int bid = blockIdx.x, tid = threadIdx.x;
    if (bid < 16) {
        gemm_bt_body<2, 1, 0>(Wq, Wp, nullptr, nullptr, WcombT, DMODEL, DMODEL, DMODEL,
                              bid & 3, bid >> 2);
    } else if (bid < 528) {
        const float* W; u16* Wt; int tb;
        if (bid < 272) { W = Wk; Wt = Wk_t; tb = bid - 16; }
        else           { W = Wv; Wt = Wv_t; tb = bid - 272; }
        int c0 = (tb & 15) * 32, r0 = (tb >> 4) * 32;
        int tx = tid & 31, ty = tid >> 5;
#pragma unroll
        for (int i = 0; i < 4; i++)
            tile[ty + i * 8][tx] = W[(size_t)(r0 + ty + i * 8) * DMODEL + c0 + tx];
        __syncthreads();
#pragma unroll
        for (int i = 0; i < 4; i++)
            Wt[(size_t)(c0 + ty + i * 8) * DMODEL + r0 + tx] = f2bf(tile[tx][ty + i * 8]);
    } else if (bid < 592) {
        int ks = (bid - 528) * 8;
        float s1 = 0.f, s2 = 0.f;
#pragma unroll
        for (int kk = 0; kk < 8; kk++) {
            float bpv = bp[ks + kk];
            s1 += bpv * Wq[(size_t)(ks + kk) * DMODEL + tid];
            s2 += bpv * Wq[(size_t)(ks + kk) * DMODEL + tid + 256];
        }
        atomicAdd(&bcomb[tid], s1);
        atomicAdd(&bcomb[tid + 256], s2);
    } else {
        // x -> bf16: 512 blocks x 256 threads x 32 elems
        size_t base = (size_t)(bid - 592) * 8192 + tid * 8;
#pragma unroll
        for (int i = 0; i < 4; i++) {
            size_t e = base + (size_t)i * 2048;
            float4 a0 = *(const float4*)(x + e);
            float4 a1 = *(const float4*)(x + e + 4);
            uint4 o;
            o.x = pk2(a0.x, a0.y); o.y = pk2(a0.z, a0.w);
            o.z = pk2(a1.x, a1.y); o.w = pk2(a1.z, a1.w);
            *(uint4*)(x_bf + e) = o;
        }
    }
}

// ---------------- K (fp8 frag-major), V (bf16 frag-major), Q (fp8) + histogram ----------------
// b 0..63: K; 64..127: V; 128..383: Q; 384..511: histogram.
__global__ __launch_bounds__(256) void k_gemm_all(
    const float* __restrict__ kb, const u16* __restrict__ Wkt, const float* __restrict__ bk,
    u8* __restrict__ Kf8,
    const float* __restrict__ vb, const u16* __restrict__ Wvt, const float* __restrict__ bv,
    u16* __restrict__ Vp,
    const u16* __restrict__ x_bf, const u16* __restrict__ WcombT,
    const float* __restrict__ bcomb, const float* __restrict__ bq_, u8* __restrict__ Qf8,
    const int* __restrict__ cidx, int* __restrict__ counts)
{
    int b = blockIdx.x;
    if (b < 64)
        gemm_bt_body<1, 0, 4>(kb, Wkt, bk, nullptr, Kf8, NC, DMODEL, DMODEL, b & 3, b >> 2);
    else if (b < 128)
        gemm_bt_body<1, 0, 1>(vb, Wvt, bv, nullptr, Vp, NC, DMODEL, DMODEL, (b - 64) & 3, (b - 64) >> 2);
    else if (b < 384)
        gemm_bt_body<0, 0, 3>(x_bf, WcombT, bcomb, bq_, Qf8, NQ, DMODEL, DMODEL, (b - 128) & 3, (b - 128) >> 2);
    else {
        for (int i = (b - 384) * 256 + threadIdx.x; i < NIDX; i += 128 * 256)
            atomicAdd(&counts[cidx[i]], 1);
    }
}

// ---------------- fused attention + LayerNorm (fp8 QK^T, bf16 PV) ----------------
// grid(NQ/32); block 512 = 8 waves = 8 heads. Wave: 32 q, one head, all 2048 c.
// QK^T in fp8 e4m3 (mfma_f32_32x32x16_fp8_fp8, same shape/lane-layout as bf16 op):
// halves K streaming bytes (L1 return path was ~90% saturated). PV stays bf16.
__global__ __launch_bounds__(512, 2) void k_attn11(
    const u8* __restrict__ Qf8, const u8* __restrict__ Kf8, const u16* __restrict__ Vp,
    const int* __restrict__ counts, const float* __restrict__ ln_g,
    const float* __restrict__ ln_b, float* __restrict__ Out, float scale2)
{
    __shared__ float sbias[NC];          // 8 KB, log2(count) - 16
    __shared__ unsigned sO[32 * 256];    // 32 KB, swizzled packed O

    int tid = threadIdx.x;
    int lane = tid & 63, wid = tid >> 6;
    int h = wid;
    int ql = lane & 31, hi = lane >> 5;
    int q0 = blockIdx.x * 32;
    int hbase = h * DH;

#pragma unroll
    for (int i = 0; i < 4; i++)
        sbias[tid + i * 512] = log2f((float)counts[tid + i * 512]) - 16.0f;

    i64 qf[4];
#pragma unroll
    for (int m = 0; m < 4; m++)
        qf[m] = *(const i64*)(Qf8 + (size_t)(q0 + ql) * DMODEL + hbase + m * 16 + hi * 8);

    const u8*  klane = Kf8 + (size_t)h * 131072 + hi * 256 + ql * 8;
    const u16* vlane = Vp  + (size_t)h * 131072 + hi * 512 + ql * 8;

    i64 kf0[4], kf1[4];
    bf16x8 vf0[4], vf1[4];
#pragma unroll
    for (int m = 0; m < 4; m++)
        kf0[m] = *(const i64*)(klane + m * 512);
#pragma unroll
    for (int T = 0; T < 2; T++)
#pragma unroll
        for (int ss = 0; ss < 2; ss++)
            vf0[T * 2 + ss] = *(const bf16x8*)(vlane + ss * 1024 + T * 256);

    f32x16 o0 = {}, o1 = {};
    float l_part = 0.f;

    __syncthreads();   // sbias ready

    auto body = [&](int t, i64 (&kfc)[4], bf16x8 (&vfc)[4],
                    i64 (&kfn)[4], bf16x8 (&vfn)[4]) {
        f32x4 bq[4];
#pragma unroll
        for (int j = 0; j < 4; j++)
            bq[j] = *(const f32x4*)(sbias + t * 32 + 8 * j + 4 * hi);

        // QK^T on current K frags (fp8 x fp8 -> f32)
        f32x16 acc = {};
        __builtin_amdgcn_s_setprio(1);
#pragma unroll
        for (int m = 0; m < 4; m++)
            acc = __builtin_amdgcn_mfma_f32_32x32x16_fp8_fp8(kfc[m], qf[m], acc, 0, 0, 0);
        __builtin_amdgcn_s_setprio(0);

        // issue next K loads (t=63 -> padded ws)
        const u8* kp = klane + (size_t)(t + 1) * 2048;
#pragma unroll
        for (int m = 0; m < 4; m++)
            kfn[m] = *(const i64*)(kp + m * 512);

        // softmax (fixed shift -16) + pack
        unsigned u[8];
        float rs0 = 0.f, rs1 = 0.f;
#pragma unroll
        for (int j = 0; j < 8; j++) {
            float p0 = exp2f(acc[2 * j] * scale2 + bq[(2 * j) >> 2][(2 * j) & 3]);
            float p1 = exp2f(acc[2 * j + 1] * scale2 + bq[(2 * j + 1) >> 2][(2 * j + 1) & 3]);
            rs0 += p0; rs1 += p1;
            u[j] = pk2(p0, p1);
        }
        l_part += rs0 + rs1;

        plswap(u[0], u[2]); plswap(u[1], u[3]);
        plswap(u[4], u[6]); plswap(u[5], u[7]);
        bf16x8 pb0 = __builtin_bit_cast(bf16x8, *(uint4*)&u[0]);
        bf16x8 pb1 = __builtin_bit_cast(bf16x8, *(uint4*)&u[4]);

        // PV on current V frags (bf16)
        __builtin_amdgcn_s_setprio(1);
        o0 = __builtin_amdgcn_mfma_f32_32x32x16_bf16(vfc[0], pb0, o0, 0, 0, 0);
        o0 = __builtin_amdgcn_mfma_f32_32x32x16_bf16(vfc[1], pb1, o0, 0, 0, 0);
        o1 = __builtin_amdgcn_mfma_f32_32x32x16_bf16(vfc[2], pb0, o1, 0, 0, 0);
        o1 = __builtin_amdgcn_mfma_f32_32x32x16_bf16(vfc[3], pb1, o1, 0, 0, 0);
        __builtin_amdgcn_s_setprio(0);

        // issue next V loads
        const u16* vp = vlane + (size_t)(t + 1) * 2048;
#pragma unroll
        for (int T = 0; T < 2; T++)
#pragma unroll
            for (int ss = 0; ss < 2; ss++)
                vfn[T * 2 + ss] = *(const bf16x8*)(vp + ss * 1024 + T * 256);
    };

    for (int t = 0; t < NC / 32; t += 2) {
        body(t,     kf0, vf0, kf1, vf1);
        body(t + 1, kf1, vf1, kf0, vf0);
    }

    float l_tot = l_part + __shfl_xor(l_part, 32);
    float inv = 1.0f / l_tot;

#pragma unroll
    for (int T = 0; T < 2; T++)
#pragma unroll
        for (int j = 0; j < 8; j++) {
            int dw = T * 16 + (j & 1) + 4 * (j >> 1) + 2 * hi;
            float a = (T == 0) ? o0[2 * j] : o1[2 * j];
            float b = (T == 0) ? o0[2 * j + 1] : o1[2 * j + 1];
            sO[soff(ql, h * 32 + dw)] = pk2(a * inv, b * inv);
        }
    __syncthreads();

    float4 g0 = *(const float4*)(ln_g + lane * 8);
    float4 g1 = *(const float4*)(ln_g + lane * 8 + 4);
    float4 b0 = *(const float4*)(ln_b + lane * 8);
    float4 b1 = *(const float4*)(ln_b + lane * 8 + 4);
#pragma unroll
    for (int rr = 0; rr < 4; rr++) {
        int r = wid * 4 + rr;
        uint4 pw = *(const uint4*)(&sO[r * 256 + ((lane ^ (r & 7)) << 2)]);
        float v[8];
        v[0] = bf2f((u16)(pw.x & 0xffff)); v[1] = bf2f((u16)(pw.x >> 16));
        v[2] = bf2f((u16)(pw.y & 0xffff)); v[3] = bf2f((u16)(pw.y >> 16));
        v[4] = bf2f((u16)(pw.z & 0xffff)); v[5] = bf2f((u16)(pw.z >> 16));
        v[6] = bf2f((u16)(pw.w & 0xffff)); v[7] = bf2f((u16)(pw.w >> 16));
        float sum = 0.f, sq = 0.f;
#pragma unroll
        for (int j = 0; j < 8; j++) { sum += v[j]; sq += v[j] * v[j]; }
#pragma unroll
        for (int msk = 1; msk <= 32; msk <<= 1) { sum += __shfl_xor(sum, msk); sq += __shfl_xor(sq, msk); }
        float mu = sum * (1.f / DMODEL);
        float var = sq * (1.f / DMODEL) - mu * mu;
        float rstd = rsqrtf(var + 1e-5f);
        float o[8];
        o[0] = (v[0] - mu) * rstd * g0.x + b0.x; o[1] = (v[1] - mu) * rstd * g0.y + b0.y;
        o[2] = (v[2] - mu) * rstd * g0.z + b0.z; o[3] = (v[3] - mu) * rstd * g0.w + b0.w;
        o[4] = (v[4] - mu) * rstd * g1.x + b1.x; o[5] = (v[5] - mu) * rstd * g1.y + b1.y;
        o[6] = (v[6] - mu) * rstd * g1.z + b1.z; o[7] = (v[7] - mu) * rstd * g1.w + b1.w;
        float* op = Out + (size_t)(q0 + r) * DMODEL + lane * 8;
        *(float4*)op = *(float4*)&o[0];
        *(float4*)(op + 4) = *(float4*)&o[4];
    }
}

extern "C" void kernel_launch(void* const* d_in, const int* in_sizes, int n_in,
                              void* d_out, int out_size, void* d_ws, size_t ws_size,
                              hipStream_t stream)
{
    const float* x      = (const float*)d_in[0];
    const float* W_proj = (const float*)d_in[1];
    const float* b_proj = (const float*)d_in[2];
    const float* W_q    = (const float*)d_in[3];
    const float* b_q    = (const float*)d_in[4];
    const float* W_k    = (const float*)d_in[5];
    const float* b_k    = (const float*)d_in[6];
    const float* W_v    = (const float*)d_in[7];
    const float* b_v    = (const float*)d_in[8];
    const float* k_buf  = (const float*)d_in[9];
    const float* v_buf  = (const float*)d_in[10];
    const float* ln_g   = (const float*)d_in[11];
    const float* ln_b   = (const float*)d_in[12];
    const int*   c_idx  = (const int*)d_in[13];
    float* out = (float*)d_out;

    char* ws = (char*)d_ws;
    size_t off = 0;
    auto alloc = [&](size_t bytes) -> void* {
        void* p = ws + off;
        off += (bytes + 255) & ~(size_t)255;
        return p;
    };
    u16* Wk_t   = (u16*)alloc((size_t)DMODEL * DMODEL * 2);
    u16* Wv_t   = (u16*)alloc((size_t)DMODEL * DMODEL * 2);
    u16* WcombT = (u16*)alloc((size_t)DMODEL * DMODEL * 2);
    u8*  Qf8    = (u8*)alloc((size_t)NQ * DMODEL);
    u8*  Kf8    = (u8*)alloc((size_t)NC * DMODEL);
    u16* Vpm    = (u16*)alloc((size_t)DMODEL * NC * 2);
    int*   counts = (int*)alloc(NC * 4);       // contiguous with bcomb: one memset
    float* bcomb  = (float*)alloc(DMODEL * 4);
    u16* x_bf   = (u16*)alloc((size_t)NQ * DMODEL * 2);
    (void)alloc(2200000);   // pad: wrap-free tail prefetch reads past Kf8/Vpm

    hipMemsetAsync(counts, 0, NC * 4 + 256 + DMODEL * 4, stream);  // counts + pad + bcomb

    k_prep2<<<dim3(1104), dim3(256), 0, stream>>>(
        W_q, W_k, W_v, W_proj, b_proj, x,
        Wk_t, Wv_t, WcombT, bcomb, x_bf);

    k_gemm_all<<<dim3(512), dim3(256), 0, stream>>>(
        k_buf, Wk_t, b_k, Kf8,
        v_buf, Wv_t, b_v, Vpm,
        x_bf, WcombT, bcomb, b_q, Qf8,
        c_idx, counts);

    // scale2 = (1/sqrt(512)) * log2(e); fixed shift folded into sbias
    k_attn11<<<dim3(NQ / 32), dim3(512), 0, stream>>>(Qf8, Kf8, Vpm, counts, ln_g, ln_b, out, 0.06375872f);
    (void)in_sizes; (void)n_in; (void)out_size; (void)ws_size;
}